// Round 1
// baseline (5367.414 us; speedup 1.0000x reference)
//
#include <hip/hip_runtime.h>

// LSTMModel: 2-layer LSTM (H1=50, H2=64) over B=2048, T=512, IN=1, + FC 64->32->16->1.
// Design: 256 blocks x 256 threads (4 waves). All recurrent weights in LDS (shared by
// the block's 4 waves). Each wave owns 2 batch elements for the whole recurrence ->
// no inter-wave synchronization inside the t-loop. h lives in one VGPR per
// (layer,batch); dot products read it cross-lane via v_readlane as the scalar FMA
// operand. Lane u owns unit u's 4 gate rows, so c/h updates are lane-local.

#define NH1 50
#define NH2 64
#define TLEN 512

// LDS float offsets: whh1 [200][50] @ 0 ; wih2 [256][50] @ 10000 ; whh2 [256][66] @ 22800
#define WIH2_OFF 10000
#define WHH2_OFF 22800
#define WHH2_LD  66
#define SMEM_FLOATS 39696   // 22800 + 256*66 = 39696 -> 158,784 bytes

__device__ __forceinline__ float rl(float v, int l) {
  return __uint_as_float(__builtin_amdgcn_readlane(__float_as_uint(v), l));
}
__device__ __forceinline__ float sigf(float x) { return 1.0f / (1.0f + __expf(-x)); }
__device__ __forceinline__ float tanh_(float x) { return 1.0f - 2.0f / (1.0f + __expf(2.0f * x)); }

__global__ __launch_bounds__(256, 1)
void lstm_fused(const float* __restrict__ x,
                const float* __restrict__ w_ih1, const float* __restrict__ w_hh1,
                const float* __restrict__ b_ih1, const float* __restrict__ b_hh1,
                const float* __restrict__ w_ih2, const float* __restrict__ w_hh2,
                const float* __restrict__ b_ih2, const float* __restrict__ b_hh2,
                const float* __restrict__ fc1_w, const float* __restrict__ fc1_b,
                const float* __restrict__ fc2_w, const float* __restrict__ fc2_b,
                const float* __restrict__ fc3_w, const float* __restrict__ fc3_b,
                float* __restrict__ out)
{
  __shared__ float smem[SMEM_FLOATS];
  const int tid = threadIdx.x;

  // ---- stage weights into LDS ----
  for (int i = tid; i < 200 * 50; i += 256) smem[i] = w_hh1[i];
  for (int i = tid; i < 256 * 50; i += 256) smem[WIH2_OFF + i] = w_ih2[i];
  for (int i = tid; i < 256 * 64; i += 256)
    smem[WHH2_OFF + (i >> 6) * WHH2_LD + (i & 63)] = w_hh2[i];
  __syncthreads();

  const int wave = tid >> 6, lane = tid & 63;
  const int b0 = blockIdx.x * 8 + wave * 2, b1 = b0 + 1;
  const int u1 = (lane < NH1) ? lane : 0;  // clamp: lanes 50..63 duplicate unit 0 (never read)

  // per-lane constants (own 4 gate rows: i,f,g,o of unit u)
  float wih1v[4], bias1[4], bias2[4];
#pragma unroll
  for (int q = 0; q < 4; ++q) {
    wih1v[q] = w_ih1[q * NH1 + u1];
    bias1[q] = b_ih1[q * NH1 + u1] + b_hh1[q * NH1 + u1];
    bias2[q] = b_ih2[q * NH2 + lane] + b_hh2[q * NH2 + lane];
  }
  const float2* wr1[4]; const float2* wr2i[4]; const float2* wr2h[4];
#pragma unroll
  for (int q = 0; q < 4; ++q) {
    wr1[q]  = (const float2*)&smem[(q * NH1 + u1) * 50];
    wr2i[q] = (const float2*)&smem[WIH2_OFF + (q * NH2 + lane) * 50];
    wr2h[q] = (const float2*)&smem[WHH2_OFF + (q * NH2 + lane) * WHH2_LD];
  }

  const float* xp0 = x + b0 * TLEN;
  const float* xp1 = x + b1 * TLEN;

  float h1v0 = 0.f, h1v1 = 0.f, c10 = 0.f, c11 = 0.f;
  float h2v0 = 0.f, h2v1 = 0.f, c20 = 0.f, c21 = 0.f;
  float xc0 = xp0[0], xc1 = xp1[0];

  for (int t = 0; t < TLEN; ++t) {
    // prefetch next x (wave-uniform scalar loads)
    float xn0 = 0.f, xn1 = 0.f;
    if (t < TLEN - 1) { xn0 = xp0[t + 1]; xn1 = xp1[t + 1]; }

    float a0[4], a1[4];
    // ---- layer 1: z = x*w_ih1 + bias + h1 @ w_hh1^T ----
#pragma unroll
    for (int q = 0; q < 4; ++q) {
      a0[q] = fmaf(xc0, wih1v[q], bias1[q]);
      a1[q] = fmaf(xc1, wih1v[q], bias1[q]);
    }
#pragma unroll
    for (int jj = 0; jj < 25; ++jj) {
      float s00 = rl(h1v0, 2 * jj), s01 = rl(h1v0, 2 * jj + 1);
      float s10 = rl(h1v1, 2 * jj), s11 = rl(h1v1, 2 * jj + 1);
#pragma unroll
      for (int q = 0; q < 4; ++q) {
        float2 w = wr1[q][jj];
        a0[q] = fmaf(s00, w.x, a0[q]); a0[q] = fmaf(s01, w.y, a0[q]);
        a1[q] = fmaf(s10, w.x, a1[q]); a1[q] = fmaf(s11, w.y, a1[q]);
      }
    }
    // gates (i,f,g,o) -> c,h   (lane-local)
    c10 = sigf(a0[1]) * c10 + sigf(a0[0]) * tanh_(a0[2]);
    h1v0 = sigf(a0[3]) * tanh_(c10);
    c11 = sigf(a1[1]) * c11 + sigf(a1[0]) * tanh_(a1[2]);
    h1v1 = sigf(a1[3]) * tanh_(c11);

    // ---- layer 2: z = h1 @ w_ih2^T + bias + h2 @ w_hh2^T ----
#pragma unroll
    for (int q = 0; q < 4; ++q) { a0[q] = bias2[q]; a1[q] = bias2[q]; }
#pragma unroll
    for (int jj = 0; jj < 25; ++jj) {
      float s00 = rl(h1v0, 2 * jj), s01 = rl(h1v0, 2 * jj + 1);
      float s10 = rl(h1v1, 2 * jj), s11 = rl(h1v1, 2 * jj + 1);
#pragma unroll
      for (int q = 0; q < 4; ++q) {
        float2 w = wr2i[q][jj];
        a0[q] = fmaf(s00, w.x, a0[q]); a0[q] = fmaf(s01, w.y, a0[q]);
        a1[q] = fmaf(s10, w.x, a1[q]); a1[q] = fmaf(s11, w.y, a1[q]);
      }
    }
#pragma unroll
    for (int jj = 0; jj < 32; ++jj) {
      float s00 = rl(h2v0, 2 * jj), s01 = rl(h2v0, 2 * jj + 1);
      float s10 = rl(h2v1, 2 * jj), s11 = rl(h2v1, 2 * jj + 1);
#pragma unroll
      for (int q = 0; q < 4; ++q) {
        float2 w = wr2h[q][jj];
        a0[q] = fmaf(s00, w.x, a0[q]); a0[q] = fmaf(s01, w.y, a0[q]);
        a1[q] = fmaf(s10, w.x, a1[q]); a1[q] = fmaf(s11, w.y, a1[q]);
      }
    }
    c20 = sigf(a0[1]) * c20 + sigf(a0[0]) * tanh_(a0[2]);
    h2v0 = sigf(a0[3]) * tanh_(c20);
    c21 = sigf(a1[1]) * c21 + sigf(a1[0]) * tanh_(a1[2]);
    h2v1 = sigf(a1[3]) * tanh_(c21);

    xc0 = xn0; xc1 = xn1;
  }

  // ---- FC head: 64 -> 32 -> 16 -> 1 (no activations) ----
  const int k1 = lane & 31;
  const float4* f1w = (const float4*)fc1_w;  // 32 rows of 16 float4
  float g10 = fc1_b[k1], g11 = g10;
#pragma unroll
  for (int jj = 0; jj < 16; ++jj) {
    float4 w = f1w[k1 * 16 + jj];
    g10 = fmaf(rl(h2v0, 4 * jj + 0), w.x, g10);
    g10 = fmaf(rl(h2v0, 4 * jj + 1), w.y, g10);
    g10 = fmaf(rl(h2v0, 4 * jj + 2), w.z, g10);
    g10 = fmaf(rl(h2v0, 4 * jj + 3), w.w, g10);
    g11 = fmaf(rl(h2v1, 4 * jj + 0), w.x, g11);
    g11 = fmaf(rl(h2v1, 4 * jj + 1), w.y, g11);
    g11 = fmaf(rl(h2v1, 4 * jj + 2), w.z, g11);
    g11 = fmaf(rl(h2v1, 4 * jj + 3), w.w, g11);
  }
  const int k2 = lane & 15;
  const float4* f2w = (const float4*)fc2_w;  // 16 rows of 8 float4
  float g20 = fc2_b[k2], g21 = g20;
#pragma unroll
  for (int jj = 0; jj < 8; ++jj) {
    float4 w = f2w[k2 * 8 + jj];
    g20 = fmaf(rl(g10, 4 * jj + 0), w.x, g20);
    g20 = fmaf(rl(g10, 4 * jj + 1), w.y, g20);
    g20 = fmaf(rl(g10, 4 * jj + 2), w.z, g20);
    g20 = fmaf(rl(g10, 4 * jj + 3), w.w, g20);
    g21 = fmaf(rl(g11, 4 * jj + 0), w.x, g21);
    g21 = fmaf(rl(g11, 4 * jj + 1), w.y, g21);
    g21 = fmaf(rl(g11, 4 * jj + 2), w.z, g21);
    g21 = fmaf(rl(g11, 4 * jj + 3), w.w, g21);
  }
  float o0 = fc3_b[0], o1 = fc3_b[0];
#pragma unroll
  for (int j = 0; j < 16; ++j) {
    float w = fc3_w[j];
    o0 = fmaf(rl(g20, j), w, o0);
    o1 = fmaf(rl(g21, j), w, o1);
  }
  if (lane == 0) { out[b0] = o0; out[b1] = o1; }
}

extern "C" void kernel_launch(void* const* d_in, const int* in_sizes, int n_in,
                              void* d_out, int out_size, void* d_ws, size_t ws_size,
                              hipStream_t stream) {
  const float* x     = (const float*)d_in[0];
  const float* w_ih1 = (const float*)d_in[1];
  const float* w_hh1 = (const float*)d_in[2];
  const float* b_ih1 = (const float*)d_in[3];
  const float* b_hh1 = (const float*)d_in[4];
  const float* w_ih2 = (const float*)d_in[5];
  const float* w_hh2 = (const float*)d_in[6];
  const float* b_ih2 = (const float*)d_in[7];
  const float* b_hh2 = (const float*)d_in[8];
  const float* fc1_w = (const float*)d_in[9];
  const float* fc1_b = (const float*)d_in[10];
  const float* fc2_w = (const float*)d_in[11];
  const float* fc2_b = (const float*)d_in[12];
  const float* fc3_w = (const float*)d_in[13];
  const float* fc3_b = (const float*)d_in[14];

  hipLaunchKernelGGL(lstm_fused, dim3(256), dim3(256), 0, stream,
                     x, w_ih1, w_hh1, b_ih1, b_hh1,
                     w_ih2, w_hh2, b_ih2, b_hh2,
                     fc1_w, fc1_b, fc2_w, fc2_b, fc3_w, fc3_b,
                     (float*)d_out);
}

// Round 2
// 2811.954 us; speedup vs baseline: 1.9088x; 1.9088x over previous
//
#include <hip/hip_runtime.h>

// LSTMModel: 2-layer LSTM (H1=50, H2=64) over B=2048, T=512, IN=1, + FC 64->32->16->1.
// 256 blocks x 256 threads (4 waves). All recurrent weights in LDS. Each wave owns
// 2 batch elements end-to-end -> no inter-wave sync in the t-loop. h lives in one
// VGPR per (layer,batch); dot products read it via v_readlane (SGPR FMA operand).
// Round 2: spill fix — no pointer arrays (base VGPR + immediate ds_read offsets),
// partial unroll (5/8) to cap the in-flight ds_read window. Round 1 spilled at
// VGPR=256 -> 12.9 GB scratch reload traffic.

#define NH1 50
#define NH2 64
#define TLEN 512

// LDS float offsets: whh1 [200][50] @ 0 ; wih2 [256][50] @ 10000 ; whh2 [256][66] @ 22800
#define WIH2_OFF 10000
#define WHH2_OFF 22800
#define WHH2_LD  66
#define SMEM_FLOATS 39696   // 158,784 bytes

__device__ __forceinline__ float rl(float v, int l) {
  return __uint_as_float(__builtin_amdgcn_readlane(__float_as_uint(v), l));
}
__device__ __forceinline__ float sigf(float x) { return 1.0f / (1.0f + __expf(-x)); }
__device__ __forceinline__ float tanh_(float x) { return 1.0f - 2.0f / (1.0f + __expf(2.0f * x)); }

__global__ __launch_bounds__(256, 1)
void lstm_fused(const float* __restrict__ x,
                const float* __restrict__ w_ih1, const float* __restrict__ w_hh1,
                const float* __restrict__ b_ih1, const float* __restrict__ b_hh1,
                const float* __restrict__ w_ih2, const float* __restrict__ w_hh2,
                const float* __restrict__ b_ih2, const float* __restrict__ b_hh2,
                const float* __restrict__ fc1_w, const float* __restrict__ fc1_b,
                const float* __restrict__ fc2_w, const float* __restrict__ fc2_b,
                const float* __restrict__ fc3_w, const float* __restrict__ fc3_b,
                float* __restrict__ out)
{
  __shared__ float smem[SMEM_FLOATS];
  const int tid = threadIdx.x;

  // ---- stage weights into LDS ----
  for (int i = tid; i < 200 * 50; i += 256) smem[i] = w_hh1[i];
  for (int i = tid; i < 256 * 50; i += 256) smem[WIH2_OFF + i] = w_ih2[i];
  for (int i = tid; i < 256 * 64; i += 256)
    smem[WHH2_OFF + (i >> 6) * WHH2_LD + (i & 63)] = w_hh2[i];
  __syncthreads();

  const int wave = tid >> 6, lane = tid & 63;
  const int b0 = blockIdx.x * 8 + wave * 2, b1 = b0 + 1;
  const int u1 = (lane < NH1) ? lane : 0;  // lanes 50..63 duplicate unit 0 (never read)

  // per-lane constants (own 4 gate rows: i,f,g,o of unit u)
  float wih1v[4], bias1[4], bias2[4];
#pragma unroll
  for (int q = 0; q < 4; ++q) {
    wih1v[q] = w_ih1[q * NH1 + u1];
    bias1[q] = b_ih1[q * NH1 + u1] + b_hh1[q * NH1 + u1];
    bias2[q] = b_ih2[q * NH2 + lane] + b_hh2[q * NH2 + lane];
  }

  // single per-lane base (float index); q-stride and jj offsets are immediates
  const int base1  = u1 * 50;                 // + q*2500 + 2*jj
  const int base2i = WIH2_OFF + lane * 50;    // + q*3200 + 2*jj
  const int base2h = WHH2_OFF + lane * WHH2_LD; // + q*4224 + 2*jj

  const float* xp0 = x + b0 * TLEN;
  const float* xp1 = x + b1 * TLEN;

  float h1v0 = 0.f, h1v1 = 0.f, c10 = 0.f, c11 = 0.f;
  float h2v0 = 0.f, h2v1 = 0.f, c20 = 0.f, c21 = 0.f;
  float xc0 = xp0[0], xc1 = xp1[0];

  for (int t = 0; t < TLEN; ++t) {
    float xn0 = 0.f, xn1 = 0.f;
    if (t < TLEN - 1) { xn0 = xp0[t + 1]; xn1 = xp1[t + 1]; }

    float a0[4], a1[4];
    // ---- layer 1: z = x*w_ih1 + bias + h1 @ w_hh1^T ----
#pragma unroll
    for (int q = 0; q < 4; ++q) {
      a0[q] = fmaf(xc0, wih1v[q], bias1[q]);
      a1[q] = fmaf(xc1, wih1v[q], bias1[q]);
    }
#pragma unroll 5
    for (int jj = 0; jj < 25; ++jj) {
      const float2 w0 = *(const float2*)&smem[base1 + 0 * 2500 + 2 * jj];
      const float2 w1 = *(const float2*)&smem[base1 + 1 * 2500 + 2 * jj];
      const float2 w2 = *(const float2*)&smem[base1 + 2 * 2500 + 2 * jj];
      const float2 w3 = *(const float2*)&smem[base1 + 3 * 2500 + 2 * jj];
      const float s00 = rl(h1v0, 2 * jj), s01 = rl(h1v0, 2 * jj + 1);
      const float s10 = rl(h1v1, 2 * jj), s11 = rl(h1v1, 2 * jj + 1);
      a0[0] = fmaf(s00, w0.x, a0[0]); a0[0] = fmaf(s01, w0.y, a0[0]);
      a0[1] = fmaf(s00, w1.x, a0[1]); a0[1] = fmaf(s01, w1.y, a0[1]);
      a0[2] = fmaf(s00, w2.x, a0[2]); a0[2] = fmaf(s01, w2.y, a0[2]);
      a0[3] = fmaf(s00, w3.x, a0[3]); a0[3] = fmaf(s01, w3.y, a0[3]);
      a1[0] = fmaf(s10, w0.x, a1[0]); a1[0] = fmaf(s11, w0.y, a1[0]);
      a1[1] = fmaf(s10, w1.x, a1[1]); a1[1] = fmaf(s11, w1.y, a1[1]);
      a1[2] = fmaf(s10, w2.x, a1[2]); a1[2] = fmaf(s11, w2.y, a1[2]);
      a1[3] = fmaf(s10, w3.x, a1[3]); a1[3] = fmaf(s11, w3.y, a1[3]);
    }
    c10 = sigf(a0[1]) * c10 + sigf(a0[0]) * tanh_(a0[2]);
    h1v0 = sigf(a0[3]) * tanh_(c10);
    c11 = sigf(a1[1]) * c11 + sigf(a1[0]) * tanh_(a1[2]);
    h1v1 = sigf(a1[3]) * tanh_(c11);

    // ---- layer 2: z = h1 @ w_ih2^T + bias + h2 @ w_hh2^T ----
#pragma unroll
    for (int q = 0; q < 4; ++q) { a0[q] = bias2[q]; a1[q] = bias2[q]; }
#pragma unroll 5
    for (int jj = 0; jj < 25; ++jj) {
      const float2 w0 = *(const float2*)&smem[base2i + 0 * 3200 + 2 * jj];
      const float2 w1 = *(const float2*)&smem[base2i + 1 * 3200 + 2 * jj];
      const float2 w2 = *(const float2*)&smem[base2i + 2 * 3200 + 2 * jj];
      const float2 w3 = *(const float2*)&smem[base2i + 3 * 3200 + 2 * jj];
      const float s00 = rl(h1v0, 2 * jj), s01 = rl(h1v0, 2 * jj + 1);
      const float s10 = rl(h1v1, 2 * jj), s11 = rl(h1v1, 2 * jj + 1);
      a0[0] = fmaf(s00, w0.x, a0[0]); a0[0] = fmaf(s01, w0.y, a0[0]);
      a0[1] = fmaf(s00, w1.x, a0[1]); a0[1] = fmaf(s01, w1.y, a0[1]);
      a0[2] = fmaf(s00, w2.x, a0[2]); a0[2] = fmaf(s01, w2.y, a0[2]);
      a0[3] = fmaf(s00, w3.x, a0[3]); a0[3] = fmaf(s01, w3.y, a0[3]);
      a1[0] = fmaf(s10, w0.x, a1[0]); a1[0] = fmaf(s11, w0.y, a1[0]);
      a1[1] = fmaf(s10, w1.x, a1[1]); a1[1] = fmaf(s11, w1.y, a1[1]);
      a1[2] = fmaf(s10, w2.x, a1[2]); a1[2] = fmaf(s11, w2.y, a1[2]);
      a1[3] = fmaf(s10, w3.x, a1[3]); a1[3] = fmaf(s11, w3.y, a1[3]);
    }
#pragma unroll 8
    for (int jj = 0; jj < 32; ++jj) {
      const float2 w0 = *(const float2*)&smem[base2h + 0 * 4224 + 2 * jj];
      const float2 w1 = *(const float2*)&smem[base2h + 1 * 4224 + 2 * jj];
      const float2 w2 = *(const float2*)&smem[base2h + 2 * 4224 + 2 * jj];
      const float2 w3 = *(const float2*)&smem[base2h + 3 * 4224 + 2 * jj];
      const float s00 = rl(h2v0, 2 * jj), s01 = rl(h2v0, 2 * jj + 1);
      const float s10 = rl(h2v1, 2 * jj), s11 = rl(h2v1, 2 * jj + 1);
      a0[0] = fmaf(s00, w0.x, a0[0]); a0[0] = fmaf(s01, w0.y, a0[0]);
      a0[1] = fmaf(s00, w1.x, a0[1]); a0[1] = fmaf(s01, w1.y, a0[1]);
      a0[2] = fmaf(s00, w2.x, a0[2]); a0[2] = fmaf(s01, w2.y, a0[2]);
      a0[3] = fmaf(s00, w3.x, a0[3]); a0[3] = fmaf(s01, w3.y, a0[3]);
      a1[0] = fmaf(s10, w0.x, a1[0]); a1[0] = fmaf(s11, w0.y, a1[0]);
      a1[1] = fmaf(s10, w1.x, a1[1]); a1[1] = fmaf(s11, w1.y, a1[1]);
      a1[2] = fmaf(s10, w2.x, a1[2]); a1[2] = fmaf(s11, w2.y, a1[2]);
      a1[3] = fmaf(s10, w3.x, a1[3]); a1[3] = fmaf(s11, w3.y, a1[3]);
    }
    c20 = sigf(a0[1]) * c20 + sigf(a0[0]) * tanh_(a0[2]);
    h2v0 = sigf(a0[3]) * tanh_(c20);
    c21 = sigf(a1[1]) * c21 + sigf(a1[0]) * tanh_(a1[2]);
    h2v1 = sigf(a1[3]) * tanh_(c21);

    xc0 = xn0; xc1 = xn1;
  }

  // ---- FC head: 64 -> 32 -> 16 -> 1 (no activations) ----
  const int k1 = lane & 31;
  const float4* f1w = (const float4*)fc1_w;  // 32 rows of 16 float4
  float g10 = fc1_b[k1], g11 = g10;
#pragma unroll
  for (int jj = 0; jj < 16; ++jj) {
    float4 w = f1w[k1 * 16 + jj];
    g10 = fmaf(rl(h2v0, 4 * jj + 0), w.x, g10);
    g10 = fmaf(rl(h2v0, 4 * jj + 1), w.y, g10);
    g10 = fmaf(rl(h2v0, 4 * jj + 2), w.z, g10);
    g10 = fmaf(rl(h2v0, 4 * jj + 3), w.w, g10);
    g11 = fmaf(rl(h2v1, 4 * jj + 0), w.x, g11);
    g11 = fmaf(rl(h2v1, 4 * jj + 1), w.y, g11);
    g11 = fmaf(rl(h2v1, 4 * jj + 2), w.z, g11);
    g11 = fmaf(rl(h2v1, 4 * jj + 3), w.w, g11);
  }
  const int k2 = lane & 15;
  const float4* f2w = (const float4*)fc2_w;  // 16 rows of 8 float4
  float g20 = fc2_b[k2], g21 = g20;
#pragma unroll
  for (int jj = 0; jj < 8; ++jj) {
    float4 w = f2w[k2 * 8 + jj];
    g20 = fmaf(rl(g10, 4 * jj + 0), w.x, g20);
    g20 = fmaf(rl(g10, 4 * jj + 1), w.y, g20);
    g20 = fmaf(rl(g10, 4 * jj + 2), w.z, g20);
    g20 = fmaf(rl(g10, 4 * jj + 3), w.w, g20);
    g21 = fmaf(rl(g11, 4 * jj + 0), w.x, g21);
    g21 = fmaf(rl(g11, 4 * jj + 1), w.y, g21);
    g21 = fmaf(rl(g11, 4 * jj + 2), w.z, g21);
    g21 = fmaf(rl(g11, 4 * jj + 3), w.w, g21);
  }
  float o0 = fc3_b[0], o1 = fc3_b[0];
#pragma unroll
  for (int j = 0; j < 16; ++j) {
    float w = fc3_w[j];
    o0 = fmaf(rl(g20, j), w, o0);
    o1 = fmaf(rl(g21, j), w, o1);
  }
  if (lane == 0) { out[b0] = o0; out[b1] = o1; }
}

extern "C" void kernel_launch(void* const* d_in, const int* in_sizes, int n_in,
                              void* d_out, int out_size, void* d_ws, size_t ws_size,
                              hipStream_t stream) {
  const float* x     = (const float*)d_in[0];
  const float* w_ih1 = (const float*)d_in[1];
  const float* w_hh1 = (const float*)d_in[2];
  const float* b_ih1 = (const float*)d_in[3];
  const float* b_hh1 = (const float*)d_in[4];
  const float* w_ih2 = (const float*)d_in[5];
  const float* w_hh2 = (const float*)d_in[6];
  const float* b_ih2 = (const float*)d_in[7];
  const float* b_hh2 = (const float*)d_in[8];
  const float* fc1_w = (const float*)d_in[9];
  const float* fc1_b = (const float*)d_in[10];
  const float* fc2_w = (const float*)d_in[11];
  const float* fc2_b = (const float*)d_in[12];
  const float* fc3_w = (const float*)d_in[13];
  const float* fc3_b = (const float*)d_in[14];

  hipLaunchKernelGGL(lstm_fused, dim3(256), dim3(256), 0, stream,
                     x, w_ih1, w_hh1, b_ih1, b_hh1,
                     w_ih2, w_hh2, b_ih2, b_hh2,
                     fc1_w, fc1_b, fc2_w, fc2_b, fc3_w, fc3_b,
                     (float*)d_out);
}

// Round 3
// 813.068 us; speedup vs baseline: 6.6014x; 3.4584x over previous
//
#include <hip/hip_runtime.h>
#include <stdint.h>

// LSTMModel via MFMA (f16 weights/h, fp32 acc/c): 2-layer LSTM (H1=50, H2=64),
// B=2048, T=512 + FC 64->32->16->1.
//
// 256 blocks x 512 threads (8 waves), Nb=8 batch cols per block (N=16 MFMA tile,
// cols 8-15 padded). Gate rows interleaved: matrix row 4u+q = gate q of unit u,
// M padded to 256. With mfma_f32_16x16x32_f16 C-layout (col=lane&15,
// row=4*(lane>>4)+reg), each lane gets all 4 gates of one unit for one batch col
// -> c/h update lane-local, no gate exchange. Weights live in VGPRs as A-frags
// (staged once through LDS). h crosses steps via f16 double-buffered LDS
// (stride 144 B for 16B-aligned b128 frag reads); ONE barrier per step.
// c state fp32 in VGPRs. Wave w owns M-tiles {2w,2w+1} = units 8w..8w+7.

typedef _Float16 f16x8 __attribute__((ext_vector_type(8)));
typedef float f32x4 __attribute__((ext_vector_type(4)));

#define TLEN 512
#define STG 0            // 256x64 f16 staging = 32768 B (reused x3, then FC scratch)
#define H1OFF 32768      // 2 bufs x 16 rows x 144 B = 4608
#define H2OFF 37376      // 4608
#define HSTR 144         // bytes per batch row (72 f16; 16B-aligned, 2-way banks)
#define HBUF 2304        // one buffer = 16*144
#define LDSB 41984

__device__ __forceinline__ float sigf(float x) { return 1.0f / (1.0f + __expf(-x)); }
__device__ __forceinline__ float tanh_(float x) { return 1.0f - 2.0f / (1.0f + __expf(2.0f * x)); }

__global__ __launch_bounds__(512, 2)
void lstm_mfma(const float* __restrict__ x,
               const float* __restrict__ w_ih1, const float* __restrict__ w_hh1,
               const float* __restrict__ b_ih1, const float* __restrict__ b_hh1,
               const float* __restrict__ w_ih2, const float* __restrict__ w_hh2,
               const float* __restrict__ b_ih2, const float* __restrict__ b_hh2,
               const float* __restrict__ fc1_w, const float* __restrict__ fc1_b,
               const float* __restrict__ fc2_w, const float* __restrict__ fc2_b,
               const float* __restrict__ fc3_w, const float* __restrict__ fc3_b,
               float* __restrict__ out)
{
  __shared__ __align__(16) char smem[LDSB];
  const int tid = threadIdx.x;
  const int wv = tid >> 6, ln = tid & 63;
  const int nn = ln & 15, g = ln >> 4;   // nn = batch col, g = lane group

  _Float16* stg = (_Float16*)(smem + STG);
  f16x8 A1[2][2], A2i[2][2], A2h[2][2];

  // ---- stage + load A-fragments (interleaved rows, zero-padded), one matrix at a time ----
  // whh1: [200x50] -> [256x64], row 4v+q = orig q*50+v
  for (int idx = tid; idx < 16384; idx += 512) {
    int R = idx >> 6, k = idx & 63, v = R >> 2, q = R & 3;
    stg[idx] = (_Float16)((v < 50 && k < 50) ? w_hh1[(q * 50 + v) * 50 + k] : 0.f);
  }
  __syncthreads();
#pragma unroll
  for (int tl = 0; tl < 2; ++tl) {
    int base = ((wv * 2 + tl) * 16 + nn) * 128;  // 128 B per row (64 f16)
    A1[tl][0] = *(const f16x8*)(smem + STG + base + g * 16);
    A1[tl][1] = *(const f16x8*)(smem + STG + base + 64 + g * 16);
  }
  __syncthreads();
  // wih2: [256x50] -> [256x64], row 4v+q = orig q*64+v
  for (int idx = tid; idx < 16384; idx += 512) {
    int R = idx >> 6, k = idx & 63, v = R >> 2, q = R & 3;
    stg[idx] = (_Float16)((k < 50) ? w_ih2[(q * 64 + v) * 50 + k] : 0.f);
  }
  __syncthreads();
#pragma unroll
  for (int tl = 0; tl < 2; ++tl) {
    int base = ((wv * 2 + tl) * 16 + nn) * 128;
    A2i[tl][0] = *(const f16x8*)(smem + STG + base + g * 16);
    A2i[tl][1] = *(const f16x8*)(smem + STG + base + 64 + g * 16);
  }
  __syncthreads();
  // whh2: [256x64] -> [256x64]
  for (int idx = tid; idx < 16384; idx += 512) {
    int R = idx >> 6, k = idx & 63, v = R >> 2, q = R & 3;
    stg[idx] = (_Float16)(w_hh2[(q * 64 + v) * 64 + k]);
  }
  // zero H buffers (9216 B = 2304 dwords) in the same pass
  for (int i = tid; i < 2304; i += 512) ((uint32_t*)(smem + H1OFF))[i] = 0;
  __syncthreads();
#pragma unroll
  for (int tl = 0; tl < 2; ++tl) {
    int base = ((wv * 2 + tl) * 16 + nn) * 128;
    A2h[tl][0] = *(const f16x8*)(smem + STG + base + g * 16);
    A2h[tl][1] = *(const f16x8*)(smem + STG + base + 64 + g * 16);
  }
  __syncthreads();

  // ---- per-lane constants: this lane's units u = 8*wv + 4*tl + g ----
  float b1c[2][4], w1c[2][4], b2c[2][4];
  int uu[2];
#pragma unroll
  for (int tl = 0; tl < 2; ++tl) {
    int u = wv * 8 + tl * 4 + g;
    uu[tl] = u;
#pragma unroll
    for (int q = 0; q < 4; ++q) {
      bool real1 = (u < 50);
      b1c[tl][q] = real1 ? (b_ih1[q * 50 + u] + b_hh1[q * 50 + u]) : 0.f;
      w1c[tl][q] = real1 ? w_ih1[q * 50 + u] : 0.f;
      b2c[tl][q] = b_ih2[q * 64 + u] + b_hh2[q * 64 + u];
    }
  }

  const float* xp = x + (blockIdx.x * 8 + (nn & 7)) * TLEN;
  float xv = xp[0];
  float c1s[2] = {0.f, 0.f}, c2s[2] = {0.f, 0.f};

  for (int t = 0; t < TLEN; ++t) {
    const int cur = t & 1, nxt = cur ^ 1;
    float xn = (t < TLEN - 1) ? xp[t + 1] : 0.f;

    // ---- phase 1: Z1 = Whh1 . H1[cur] ; h1 update -> H1[nxt] ----
    const char* h1b = smem + H1OFF + cur * HBUF + nn * HSTR;
    f16x8 b0 = *(const f16x8*)(h1b + g * 16);
    f16x8 b1 = *(const f16x8*)(h1b + 64 + g * 16);
    f32x4 acc0 = {0.f, 0.f, 0.f, 0.f}, acc1 = {0.f, 0.f, 0.f, 0.f};
    acc0 = __builtin_amdgcn_mfma_f32_16x16x32_f16(A1[0][0], b0, acc0, 0, 0, 0);
    acc0 = __builtin_amdgcn_mfma_f32_16x16x32_f16(A1[0][1], b1, acc0, 0, 0, 0);
    acc1 = __builtin_amdgcn_mfma_f32_16x16x32_f16(A1[1][0], b0, acc1, 0, 0, 0);
    acc1 = __builtin_amdgcn_mfma_f32_16x16x32_f16(A1[1][1], b1, acc1, 0, 0, 0);
#pragma unroll
    for (int tl = 0; tl < 2; ++tl) {
      f32x4 a = tl ? acc1 : acc0;
      float z0 = a[0] + b1c[tl][0] + w1c[tl][0] * xv;
      float z1 = a[1] + b1c[tl][1] + w1c[tl][1] * xv;
      float z2 = a[2] + b1c[tl][2] + w1c[tl][2] * xv;
      float z3 = a[3] + b1c[tl][3] + w1c[tl][3] * xv;
      float c = sigf(z1) * c1s[tl] + sigf(z0) * tanh_(z2);
      c1s[tl] = c;
      float h = sigf(z3) * tanh_(c);
      *(_Float16*)(smem + H1OFF + nxt * HBUF + nn * HSTR + uu[tl] * 2) = (_Float16)h;
    }
    __syncthreads();   // H1[nxt] complete (the only barrier per step)

    // ---- phase 2: Z2 = Wih2 . H1[nxt] + Whh2 . H2[cur] ; h2 -> H2[nxt] ----
    const char* h1n = smem + H1OFF + nxt * HBUF + nn * HSTR;
    const char* h2b = smem + H2OFF + cur * HBUF + nn * HSTR;
    f16x8 p0 = *(const f16x8*)(h1n + g * 16);
    f16x8 p1 = *(const f16x8*)(h1n + 64 + g * 16);
    f16x8 q0 = *(const f16x8*)(h2b + g * 16);
    f16x8 q1 = *(const f16x8*)(h2b + 64 + g * 16);
    f32x4 d0 = {0.f, 0.f, 0.f, 0.f}, d1 = {0.f, 0.f, 0.f, 0.f};
    d0 = __builtin_amdgcn_mfma_f32_16x16x32_f16(A2i[0][0], p0, d0, 0, 0, 0);
    d0 = __builtin_amdgcn_mfma_f32_16x16x32_f16(A2i[0][1], p1, d0, 0, 0, 0);
    d0 = __builtin_amdgcn_mfma_f32_16x16x32_f16(A2h[0][0], q0, d0, 0, 0, 0);
    d0 = __builtin_amdgcn_mfma_f32_16x16x32_f16(A2h[0][1], q1, d0, 0, 0, 0);
    d1 = __builtin_amdgcn_mfma_f32_16x16x32_f16(A2i[1][0], p0, d1, 0, 0, 0);
    d1 = __builtin_amdgcn_mfma_f32_16x16x32_f16(A2i[1][1], p1, d1, 0, 0, 0);
    d1 = __builtin_amdgcn_mfma_f32_16x16x32_f16(A2h[1][0], q0, d1, 0, 0, 0);
    d1 = __builtin_amdgcn_mfma_f32_16x16x32_f16(A2h[1][1], q1, d1, 0, 0, 0);
#pragma unroll
    for (int tl = 0; tl < 2; ++tl) {
      f32x4 a = tl ? d1 : d0;
      float z0 = a[0] + b2c[tl][0];
      float z1 = a[1] + b2c[tl][1];
      float z2 = a[2] + b2c[tl][2];
      float z3 = a[3] + b2c[tl][3];
      float c = sigf(z1) * c2s[tl] + sigf(z0) * tanh_(z2);
      c2s[tl] = c;
      float h = sigf(z3) * tanh_(c);
      *(_Float16*)(smem + H2OFF + nxt * HBUF + nn * HSTR + uu[tl] * 2) = (_Float16)h;
      if (t == TLEN - 1)  // stash fp32 h2 for the FC head (stage region is free now)
        ((float*)smem)[nn * 64 + uu[tl]] = h;
    }
    // no end barrier needed: next phase1 touches only H1 buffers; next phase2's
    // reads of H2[nxt] are ordered by next step's barrier.
    xv = xn;
  }
  __syncthreads();

  // ---- FC head: 64 -> 32 -> 16 -> 1 on fp32 h2 (smem[0..4095] = h2f[16][64]) ----
  float* h2f = (float*)smem;                 // [16][64] (n>=8 are pad garbage, unused)
  float* f1o = (float*)(smem + 4096);        // [8][32]
  float* f2o = (float*)(smem + 4096 + 1024); // [8][16]
  if (tid < 256) {
    int o = tid & 31, n = tid >> 5;
    float s = fc1_b[o];
#pragma unroll 8
    for (int k = 0; k < 64; ++k) s = fmaf(h2f[n * 64 + k], fc1_w[o * 64 + k], s);
    f1o[n * 32 + o] = s;
  }
  __syncthreads();
  if (tid < 128) {
    int o = tid & 15, n = tid >> 4;
    float s = fc2_b[o];
#pragma unroll 8
    for (int k = 0; k < 32; ++k) s = fmaf(f1o[n * 32 + k], fc2_w[o * 32 + k], s);
    f2o[n * 16 + o] = s;
  }
  __syncthreads();
  if (tid < 8) {
    float s = fc3_b[0];
#pragma unroll
    for (int k = 0; k < 16; ++k) s = fmaf(f2o[tid * 16 + k], fc3_w[k], s);
    out[blockIdx.x * 8 + tid] = s;
  }
}

extern "C" void kernel_launch(void* const* d_in, const int* in_sizes, int n_in,
                              void* d_out, int out_size, void* d_ws, size_t ws_size,
                              hipStream_t stream) {
  const float* x     = (const float*)d_in[0];
  const float* w_ih1 = (const float*)d_in[1];
  const float* w_hh1 = (const float*)d_in[2];
  const float* b_ih1 = (const float*)d_in[3];
  const float* b_hh1 = (const float*)d_in[4];
  const float* w_ih2 = (const float*)d_in[5];
  const float* w_hh2 = (const float*)d_in[6];
  const float* b_ih2 = (const float*)d_in[7];
  const float* b_hh2 = (const float*)d_in[8];
  const float* fc1_w = (const float*)d_in[9];
  const float* fc1_b = (const float*)d_in[10];
  const float* fc2_w = (const float*)d_in[11];
  const float* fc2_b = (const float*)d_in[12];
  const float* fc3_w = (const float*)d_in[13];
  const float* fc3_b = (const float*)d_in[14];

  hipLaunchKernelGGL(lstm_mfma, dim3(256), dim3(512), 0, stream,
                     x, w_ih1, w_hh1, b_ih1, b_hh1,
                     w_ih2, w_hh2, b_ih2, b_hh2,
                     fc1_w, fc1_b, fc2_w, fc2_b, fc3_w, fc3_b,
                     (float*)d_out);
}

// Round 4
// 766.733 us; speedup vs baseline: 7.0004x; 1.0604x over previous
//
#include <hip/hip_runtime.h>
#include <stdint.h>

// LSTMModel via MFMA (f16 weights/h, fp32 acc/c): 2-layer LSTM (H1=50, H2=64),
// B=2048, T=512 + FC 64->32->16->1.
//
// Round 4: skewed pipeline. At iter t one merged region computes h1(t) AND
// h2(t-1) (layer2 runs one step behind): both consume h1(t-1), so the B-frags
// b0,b1 are SHARED (4 ds_read_b128/step instead of 6), all 12 MFMAs issue in
// one block, activations of both layers overlap (4-way ILP), and there is ONE
// barrier per step with no mid-step serialization. x is loaded 8 steps at a
// time (2x float4, statically indexed by 8x unroll) so barriers don't drain an
// outstanding global load. Invariant: h1(tau) lives in H1[(tau+1)&1],
// h2(tau) in H2[(tau+1)&1]; at iter t (cur=t&1): read h1(t-1)=H1[cur],
// h2(t-2)=H2[cur^1]; write h1(t)->H1[cur^1], h2(t-1)->H2[cur]. t=0 select
// forces h2(-1)=0; epilogue computes h2(511) and stashes fp32 for the FC head.

typedef _Float16 f16x8 __attribute__((ext_vector_type(8)));
typedef float f32x4 __attribute__((ext_vector_type(4)));

#define TLEN 512
#define STG 0            // 256x64 f16 staging = 32768 B (reused as FC scratch)
#define H1OFF 32768      // 2 bufs x 16 rows x 144 B
#define H2OFF 37376
#define HSTR 144
#define HBUF 2304
#define LDSB 41984

__device__ __forceinline__ float sigf(float x) { return 1.0f / (1.0f + __expf(-x)); }
__device__ __forceinline__ float tanh_(float x) { return 1.0f - 2.0f / (1.0f + __expf(2.0f * x)); }

#define MFMA16(A, B, C) __builtin_amdgcn_mfma_f32_16x16x32_f16(A, B, C, 0, 0, 0)

__global__ __launch_bounds__(512, 2)
void lstm_mfma(const float* __restrict__ x,
               const float* __restrict__ w_ih1, const float* __restrict__ w_hh1,
               const float* __restrict__ b_ih1, const float* __restrict__ b_hh1,
               const float* __restrict__ w_ih2, const float* __restrict__ w_hh2,
               const float* __restrict__ b_ih2, const float* __restrict__ b_hh2,
               const float* __restrict__ fc1_w, const float* __restrict__ fc1_b,
               const float* __restrict__ fc2_w, const float* __restrict__ fc2_b,
               const float* __restrict__ fc3_w, const float* __restrict__ fc3_b,
               float* __restrict__ out)
{
  __shared__ __align__(16) char smem[LDSB];
  const int tid = threadIdx.x;
  const int wv = tid >> 6, ln = tid & 63;
  const int nn = ln & 15, g = ln >> 4;

  _Float16* stg = (_Float16*)(smem + STG);
  f16x8 A1[2][2], A2i[2][2], A2h[2][2];

  // ---- stage + load A-fragments (gate-interleaved rows, zero-padded) ----
  for (int idx = tid; idx < 16384; idx += 512) {
    int R = idx >> 6, k = idx & 63, v = R >> 2, q = R & 3;
    stg[idx] = (_Float16)((v < 50 && k < 50) ? w_hh1[(q * 50 + v) * 50 + k] : 0.f);
  }
  __syncthreads();
#pragma unroll
  for (int tl = 0; tl < 2; ++tl) {
    int base = ((wv * 2 + tl) * 16 + nn) * 128;
    A1[tl][0] = *(const f16x8*)(smem + STG + base + g * 16);
    A1[tl][1] = *(const f16x8*)(smem + STG + base + 64 + g * 16);
  }
  __syncthreads();
  for (int idx = tid; idx < 16384; idx += 512) {
    int R = idx >> 6, k = idx & 63, v = R >> 2, q = R & 3;
    stg[idx] = (_Float16)((k < 50) ? w_ih2[(q * 64 + v) * 50 + k] : 0.f);
  }
  __syncthreads();
#pragma unroll
  for (int tl = 0; tl < 2; ++tl) {
    int base = ((wv * 2 + tl) * 16 + nn) * 128;
    A2i[tl][0] = *(const f16x8*)(smem + STG + base + g * 16);
    A2i[tl][1] = *(const f16x8*)(smem + STG + base + 64 + g * 16);
  }
  __syncthreads();
  for (int idx = tid; idx < 16384; idx += 512) {
    int R = idx >> 6, k = idx & 63, v = R >> 2, q = R & 3;
    stg[idx] = (_Float16)(w_hh2[(q * 64 + v) * 64 + k]);
  }
  for (int i = tid; i < 2304; i += 512) ((uint32_t*)(smem + H1OFF))[i] = 0;  // zero H1/H2
  __syncthreads();
#pragma unroll
  for (int tl = 0; tl < 2; ++tl) {
    int base = ((wv * 2 + tl) * 16 + nn) * 128;
    A2h[tl][0] = *(const f16x8*)(smem + STG + base + g * 16);
    A2h[tl][1] = *(const f16x8*)(smem + STG + base + 64 + g * 16);
  }
  __syncthreads();

  // ---- per-lane constants: units u = 8*wv + 4*tl + g ----
  float b1c[2][4], w1c[2][4], b2c[2][4];
  int uu[2];
#pragma unroll
  for (int tl = 0; tl < 2; ++tl) {
    int u = wv * 8 + tl * 4 + g;
    uu[tl] = u;
#pragma unroll
    for (int q = 0; q < 4; ++q) {
      bool real1 = (u < 50);
      b1c[tl][q] = real1 ? (b_ih1[q * 50 + u] + b_hh1[q * 50 + u]) : 0.f;
      w1c[tl][q] = real1 ? w_ih1[q * 50 + u] : 0.f;
      b2c[tl][q] = b_ih2[q * 64 + u] + b_hh2[q * 64 + u];
    }
  }

  const float* xp = x + (blockIdx.x * 8 + (nn & 7)) * TLEN;
  float c1s[2] = {0.f, 0.f}, c2s[2] = {0.f, 0.f};

  const char* const h1base = smem + H1OFF + nn * HSTR;
  const char* const h2base = smem + H2OFF + nn * HSTR;

  for (int tb = 0; tb < TLEN; tb += 8) {
    const float4 xa = *(const float4*)&xp[tb];
    const float4 xb = *(const float4*)&xp[tb + 4];
    const float x8[8] = {xa.x, xa.y, xa.z, xa.w, xb.x, xb.y, xb.z, xb.w};
#pragma unroll
    for (int k = 0; k < 8; ++k) {
      const int cur = k & 1;                    // tb even -> cur == t&1
      const bool first = (k == 0) && (tb == 0); // folds to false for k>0

      // ---- shared reads: b = h1(t-1), q = h2(t-2) ----
      const char* hb = h1base + cur * HBUF;
      const char* qb = h2base + (cur ^ 1) * HBUF;
      const f16x8 b0 = *(const f16x8*)(hb + g * 16);
      const f16x8 b1 = *(const f16x8*)(hb + 64 + g * 16);
      const f16x8 q0 = *(const f16x8*)(qb + g * 16);
      const f16x8 q1 = *(const f16x8*)(qb + 64 + g * 16);

      // ---- all 12 MFMAs (chains <= 2 deep) ----
      f32x4 acc0 = {0.f, 0.f, 0.f, 0.f}, acc1 = {0.f, 0.f, 0.f, 0.f};
      f32x4 d0a = {0.f, 0.f, 0.f, 0.f}, d0b = {0.f, 0.f, 0.f, 0.f};
      f32x4 d1a = {0.f, 0.f, 0.f, 0.f}, d1b = {0.f, 0.f, 0.f, 0.f};
      acc0 = MFMA16(A1[0][0], b0, acc0);  acc0 = MFMA16(A1[0][1], b1, acc0);
      acc1 = MFMA16(A1[1][0], b0, acc1);  acc1 = MFMA16(A1[1][1], b1, acc1);
      d0a  = MFMA16(A2i[0][0], b0, d0a);  d0a  = MFMA16(A2i[0][1], b1, d0a);
      d0b  = MFMA16(A2h[0][0], q0, d0b);  d0b  = MFMA16(A2h[0][1], q1, d0b);
      d1a  = MFMA16(A2i[1][0], b0, d1a);  d1a  = MFMA16(A2i[1][1], b1, d1a);
      d1b  = MFMA16(A2h[1][0], q0, d1b);  d1b  = MFMA16(A2h[1][1], q1, d1b);

      const float xv = x8[k];
      // ---- layer 1 activations: h1(t) -> H1[cur^1] ----
#pragma unroll
      for (int tl = 0; tl < 2; ++tl) {
        const f32x4 a = tl ? acc1 : acc0;
        float z0 = a[0] + b1c[tl][0] + w1c[tl][0] * xv;
        float z1 = a[1] + b1c[tl][1] + w1c[tl][1] * xv;
        float z2 = a[2] + b1c[tl][2] + w1c[tl][2] * xv;
        float z3 = a[3] + b1c[tl][3] + w1c[tl][3] * xv;
        float c = sigf(z1) * c1s[tl] + sigf(z0) * tanh_(z2);
        c1s[tl] = c;
        float h = sigf(z3) * tanh_(c);
        *(_Float16*)(smem + H1OFF + (cur ^ 1) * HBUF + nn * HSTR + uu[tl] * 2) = (_Float16)h;
      }
      // ---- layer 2 activations: h2(t-1) -> H2[cur] (t=0: force h2(-1)=0) ----
#pragma unroll
      for (int tl = 0; tl < 2; ++tl) {
        const f32x4 da = tl ? d1a : d0a;
        const f32x4 db = tl ? d1b : d0b;
        float z0 = da[0] + db[0] + b2c[tl][0];
        float z1 = da[1] + db[1] + b2c[tl][1];
        float z2 = da[2] + db[2] + b2c[tl][2];
        float z3 = da[3] + db[3] + b2c[tl][3];
        float c = sigf(z1) * c2s[tl] + sigf(z0) * tanh_(z2);
        float h = sigf(z3) * tanh_(c);
        if (first) { c = 0.f; h = 0.f; }
        c2s[tl] = c;
        *(_Float16*)(smem + H2OFF + cur * HBUF + nn * HSTR + uu[tl] * 2) = (_Float16)h;
      }
      __syncthreads();   // the ONE barrier per step
    }
  }

  // ---- epilogue: h2(511) from h1(511)=H1[0], h2(510)=H2[1] ----
  {
    const char* hb = h1base;          // H1[0]
    const char* qb = h2base + HBUF;   // H2[1]
    const f16x8 b0 = *(const f16x8*)(hb + g * 16);
    const f16x8 b1 = *(const f16x8*)(hb + 64 + g * 16);
    const f16x8 q0 = *(const f16x8*)(qb + g * 16);
    const f16x8 q1 = *(const f16x8*)(qb + 64 + g * 16);
    f32x4 d0a = {0.f, 0.f, 0.f, 0.f}, d0b = {0.f, 0.f, 0.f, 0.f};
    f32x4 d1a = {0.f, 0.f, 0.f, 0.f}, d1b = {0.f, 0.f, 0.f, 0.f};
    d0a = MFMA16(A2i[0][0], b0, d0a);  d0a = MFMA16(A2i[0][1], b1, d0a);
    d0b = MFMA16(A2h[0][0], q0, d0b);  d0b = MFMA16(A2h[0][1], q1, d0b);
    d1a = MFMA16(A2i[1][0], b0, d1a);  d1a = MFMA16(A2i[1][1], b1, d1a);
    d1b = MFMA16(A2h[1][0], q0, d1b);  d1b = MFMA16(A2h[1][1], q1, d1b);
    __syncthreads();   // everyone done reading H buffers; stg region reusable
#pragma unroll
    for (int tl = 0; tl < 2; ++tl) {
      const f32x4 da = tl ? d1a : d0a;
      const f32x4 db = tl ? d1b : d0b;
      float z0 = da[0] + db[0] + b2c[tl][0];
      float z1 = da[1] + db[1] + b2c[tl][1];
      float z2 = da[2] + db[2] + b2c[tl][2];
      float z3 = da[3] + db[3] + b2c[tl][3];
      float c = sigf(z1) * c2s[tl] + sigf(z0) * tanh_(z2);
      float h = sigf(z3) * tanh_(c);
      ((float*)smem)[nn * 64 + uu[tl]] = h;   // fp32 h2(511) for FC head
    }
  }
  __syncthreads();

  // ---- FC head: 64 -> 32 -> 16 -> 1 ----
  float* h2f = (float*)smem;                 // [16][64]
  float* f1o = (float*)(smem + 4096);        // [8][32]
  float* f2o = (float*)(smem + 4096 + 1024); // [8][16]
  if (tid < 256) {
    int o = tid & 31, n = tid >> 5;
    float s = fc1_b[o];
#pragma unroll 8
    for (int k = 0; k < 64; ++k) s = fmaf(h2f[n * 64 + k], fc1_w[o * 64 + k], s);
    f1o[n * 32 + o] = s;
  }
  __syncthreads();
  if (tid < 128) {
    int o = tid & 15, n = tid >> 4;
    float s = fc2_b[o];
#pragma unroll 8
    for (int k = 0; k < 32; ++k) s = fmaf(f1o[n * 32 + k], fc2_w[o * 32 + k], s);
    f2o[n * 16 + o] = s;
  }
  __syncthreads();
  if (tid < 8) {
    float s = fc3_b[0];
#pragma unroll
    for (int k = 0; k < 16; ++k) s = fmaf(f2o[tid * 16 + k], fc3_w[k], s);
    out[blockIdx.x * 8 + tid] = s;
  }
}

extern "C" void kernel_launch(void* const* d_in, const int* in_sizes, int n_in,
                              void* d_out, int out_size, void* d_ws, size_t ws_size,
                              hipStream_t stream) {
  const float* x     = (const float*)d_in[0];
  const float* w_ih1 = (const float*)d_in[1];
  const float* w_hh1 = (const float*)d_in[2];
  const float* b_ih1 = (const float*)d_in[3];
  const float* b_hh1 = (const float*)d_in[4];
  const float* w_ih2 = (const float*)d_in[5];
  const float* w_hh2 = (const float*)d_in[6];
  const float* b_ih2 = (const float*)d_in[7];
  const float* b_hh2 = (const float*)d_in[8];
  const float* fc1_w = (const float*)d_in[9];
  const float* fc1_b = (const float*)d_in[10];
  const float* fc2_w = (const float*)d_in[11];
  const float* fc2_b = (const float*)d_in[12];
  const float* fc3_w = (const float*)d_in[13];
  const float* fc3_b = (const float*)d_in[14];

  hipLaunchKernelGGL(lstm_mfma, dim3(256), dim3(512), 0, stream,
                     x, w_ih1, w_hh1, b_ih1, b_hh1,
                     w_ih2, w_hh2, b_ih2, b_hh2,
                     fc1_w, fc1_b, fc2_w, fc2_b, fc3_w, fc3_b,
                     (float*)d_out);
}

// Round 5
// 362.136 us; speedup vs baseline: 14.8215x; 2.1173x over previous
//
#include <hip/hip_runtime.h>
#include <stdint.h>

// LSTMModel via MFMA (f16 weights/h, fp32 acc/c): 2-layer LSTM (H1=50, H2=64),
// B=2048, T=512 + FC 64->32->16->1.
//
// Round 5: 256 blocks x 1024 threads (16 waves, 4/SIMD). Wave w owns ONE M-tile
// (units u=4w+g). Skewed pipeline (layer2 one step behind) with ONE barrier per
// step. All lanes compute the layer-2 MFMA chain (C-input = bias vector); waves
// 0..12 also compute layer-1 (C-input = fma(w_ih1,x,bias) seed). shfl_xor(d,8)
// ships layer-2 z's from real cols (nn<8) to pad-col lanes (nn>=8): lanes nn<8
// update LAYER 1, lanes nn>=8 update LAYER 2 -> exactly one unit-update per
// lane per step. Sigmoid/tanh use v_rcp_f32 instead of IEEE divide.
// Invariant: h1(tau) in H1[(tau+1)&1], h2(tau) in H2[(tau+1)&1]. At iter t
// (cur=t&1): read h1(t-1)=H1[cur], h2(t-2)=H2[cur^1]; write h1(t)->H1[cur^1]
// (lower lanes), h2(t-1)->H2[cur] (upper lanes). t=0 forces c2=0 (h2(-1)=0).

typedef _Float16 f16x8 __attribute__((ext_vector_type(8)));
typedef float f32x4 __attribute__((ext_vector_type(4)));

#define TLEN 512
#define STG 0            // 256x64 f16 staging = 32768 B (later: FC scratch)
#define H1OFF 32768      // 2 bufs x 16 rows x 144 B
#define H2OFF 37376
#define HSTR 144
#define HBUF 2304
#define LDSB 41984

__device__ __forceinline__ float rcpf_(float x) {
#if __has_builtin(__builtin_amdgcn_rcpf)
  return __builtin_amdgcn_rcpf(x);
#else
  return __fdividef(1.0f, x);
#endif
}
__device__ __forceinline__ float sigf(float z)   { return rcpf_(1.0f + __expf(-z)); }
__device__ __forceinline__ float tanhf_(float z) { return 1.0f - 2.0f * rcpf_(1.0f + __expf(2.0f * z)); }

#define MFMA16(A, B, C) __builtin_amdgcn_mfma_f32_16x16x32_f16(A, B, C, 0, 0, 0)

__global__ __launch_bounds__(1024, 1)
void lstm_mfma(const float* __restrict__ x,
               const float* __restrict__ w_ih1, const float* __restrict__ w_hh1,
               const float* __restrict__ b_ih1, const float* __restrict__ b_hh1,
               const float* __restrict__ w_ih2, const float* __restrict__ w_hh2,
               const float* __restrict__ b_ih2, const float* __restrict__ b_hh2,
               const float* __restrict__ fc1_w, const float* __restrict__ fc1_b,
               const float* __restrict__ fc2_w, const float* __restrict__ fc2_b,
               const float* __restrict__ fc3_w, const float* __restrict__ fc3_b,
               float* __restrict__ out)
{
  __shared__ __align__(16) char smem[LDSB];
  const int tid = threadIdx.x;
  const int wv = tid >> 6, ln = tid & 63;
  const int nn = ln & 15, g = ln >> 4;
  const int u = wv * 4 + g;               // this lane's unit (both layers)
  const bool isUpper = (nn >= 8);         // upper half-cols: layer-2 duty
  const bool hasL1 = (wv <= 12);          // waves 13..15: layer-1 tile is all zero

  _Float16* stg = (_Float16*)(smem + STG);
  f16x8 A1[2], A2i[2], A2h[2];

  // ---- stage + load A-fragments (gate-interleaved rows 4v+q, zero-padded) ----
  for (int idx = tid; idx < 16384; idx += 1024) {
    int R = idx >> 6, k = idx & 63, v = R >> 2, q = R & 3;
    stg[idx] = (_Float16)((v < 50 && k < 50) ? w_hh1[(q * 50 + v) * 50 + k] : 0.f);
  }
  __syncthreads();
  {
    int base = (wv * 16 + nn) * 128 + g * 16;
    A1[0] = *(const f16x8*)(smem + STG + base);
    A1[1] = *(const f16x8*)(smem + STG + base + 64);
  }
  __syncthreads();
  for (int idx = tid; idx < 16384; idx += 1024) {
    int R = idx >> 6, k = idx & 63, v = R >> 2, q = R & 3;
    stg[idx] = (_Float16)((k < 50) ? w_ih2[(q * 64 + v) * 50 + k] : 0.f);
  }
  __syncthreads();
  {
    int base = (wv * 16 + nn) * 128 + g * 16;
    A2i[0] = *(const f16x8*)(smem + STG + base);
    A2i[1] = *(const f16x8*)(smem + STG + base + 64);
  }
  __syncthreads();
  for (int idx = tid; idx < 16384; idx += 1024) {
    int R = idx >> 6, k = idx & 63, v = R >> 2, q = R & 3;
    stg[idx] = (_Float16)(w_hh2[(q * 64 + v) * 64 + k]);
  }
  for (int i = tid; i < 2304; i += 1024) ((uint32_t*)(smem + H1OFF))[i] = 0;  // zero H1+H2
  __syncthreads();
  {
    int base = (wv * 16 + nn) * 128 + g * 16;
    A2h[0] = *(const f16x8*)(smem + STG + base);
    A2h[1] = *(const f16x8*)(smem + STG + base + 64);
  }
  __syncthreads();

  // ---- per-lane constants for unit u ----
  float w1c[4], b1c[4];
  f32x4 b2v;
#pragma unroll
  for (int q = 0; q < 4; ++q) {
    bool r1 = (u < 50);
    w1c[q] = r1 ? w_ih1[q * 50 + u] : 0.f;
    b1c[q] = r1 ? (b_ih1[q * 50 + u] + b_hh1[q * 50 + u]) : 0.f;
    b2v[q] = b_ih2[q * 64 + u] + b_hh2[q * 64 + u];
  }

  const float* xp = x + (blockIdx.x * 8 + (nn & 7)) * TLEN;

  // write pointers for cur=0 / cur=1 (lower: h1(t)->H1[cur^1]; upper: h2(t-1)->H2[cur])
  _Float16 *wp0, *wp1;
  if (!isUpper) {
    wp0 = (_Float16*)(smem + H1OFF + HBUF + nn * HSTR + u * 2);
    wp1 = (_Float16*)(smem + H1OFF +    0 + nn * HSTR + u * 2);
  } else {
    wp0 = (_Float16*)(smem + H2OFF +    0 + (nn - 8) * HSTR + u * 2);
    wp1 = (_Float16*)(smem + H2OFF + HBUF + (nn - 8) * HSTR + u * 2);
  }
  const bool doWrite = isUpper || hasL1;

  const char* const h1b = smem + H1OFF + nn * HSTR;
  const char* const h2b = smem + H2OFF + nn * HSTR;

  float cs = 0.f;                       // c1 (lower lanes) or c2 (upper lanes)
  f32x4 acc = {0.f, 0.f, 0.f, 0.f};     // layer-1 z (stays 0 for waves 13..15)

  for (int tb = 0; tb < TLEN; tb += 8) {
    const float4 xa = *(const float4*)&xp[tb];
    const float4 xb = *(const float4*)&xp[tb + 4];
    const float x8[8] = {xa.x, xa.y, xa.z, xa.w, xb.x, xb.y, xb.z, xb.w};
#pragma unroll
    for (int k = 0; k < 8; ++k) {
      const int cur = k & 1;
      const bool first = (tb == 0) && (k == 0);

      const f16x8 b0 = *(const f16x8*)(h1b + cur * HBUF + g * 16);
      const f16x8 b1 = *(const f16x8*)(h1b + cur * HBUF + 64 + g * 16);
      const f16x8 q0 = *(const f16x8*)(h2b + (cur ^ 1) * HBUF + g * 16);
      const f16x8 q1 = *(const f16x8*)(h2b + (cur ^ 1) * HBUF + 64 + g * 16);

      // layer-2 chain (all lanes), C seeded with bias
      f32x4 d = MFMA16(A2i[0], b0, b2v);
      d = MFMA16(A2i[1], b1, d);
      d = MFMA16(A2h[0], q0, d);
      d = MFMA16(A2h[1], q1, d);

      // layer-1 chain (waves 0..12), C seeded with w_ih1*x + bias
      if (hasL1) {
        const float xv = x8[k];
        f32x4 s;
        s[0] = fmaf(w1c[0], xv, b1c[0]);
        s[1] = fmaf(w1c[1], xv, b1c[1]);
        s[2] = fmaf(w1c[2], xv, b1c[2]);
        s[3] = fmaf(w1c[3], xv, b1c[3]);
        acc = MFMA16(A1[0], b0, s);
        acc = MFMA16(A1[1], b1, acc);
      }

      // ship layer-2 z's from real cols (nn<8) to pad-col lanes (all lanes execute)
      const float dr0 = __shfl_xor(d[0], 8, 64);
      const float dr1 = __shfl_xor(d[1], 8, 64);
      const float dr2 = __shfl_xor(d[2], 8, 64);
      const float dr3 = __shfl_xor(d[3], 8, 64);

      const float z0 = isUpper ? dr0 : acc[0];
      const float z1 = isUpper ? dr1 : acc[1];
      const float z2 = isUpper ? dr2 : acc[2];
      const float z3 = isUpper ? dr3 : acc[3];

      // one unit-update per lane: i,f,g,o -> c,h
      const float gi = sigf(z0), gf = sigf(z1), gg = tanhf_(z2), go = sigf(z3);
      float c = gf * cs + gi * gg;
      if (first) { if (isUpper) c = 0.f; }   // h2(-1)=0 (h follows via tanh(0))
      cs = c;
      const float h = go * tanhf_(c);
      if (doWrite) *(cur ? wp1 : wp0) = (_Float16)h;
      __syncthreads();   // the ONE barrier per step
    }
  }

  // ---- epilogue: h2(511) from h1(511)=H1[0], h2(510)=H2[1] ----
  {
    const f16x8 b0 = *(const f16x8*)(h1b + g * 16);
    const f16x8 b1 = *(const f16x8*)(h1b + 64 + g * 16);
    const f16x8 q0 = *(const f16x8*)(h2b + HBUF + g * 16);
    const f16x8 q1 = *(const f16x8*)(h2b + HBUF + 64 + g * 16);
    f32x4 d = MFMA16(A2i[0], b0, b2v);
    d = MFMA16(A2i[1], b1, d);
    d = MFMA16(A2h[0], q0, d);
    d = MFMA16(A2h[1], q1, d);
    const float dr0 = __shfl_xor(d[0], 8, 64);
    const float dr1 = __shfl_xor(d[1], 8, 64);
    const float dr2 = __shfl_xor(d[2], 8, 64);
    const float dr3 = __shfl_xor(d[3], 8, 64);
    if (isUpper) {
      const float gi = sigf(dr0), gf = sigf(dr1), gg = tanhf_(dr2), go = sigf(dr3);
      const float c = gf * cs + gi * gg;
      const float h = go * tanhf_(c);
      ((float*)smem)[(nn - 8) * 64 + u] = h;   // fp32 h2(511): [8][64]
    }
  }
  __syncthreads();

  // ---- FC head: 64 -> 32 -> 16 -> 1 ----
  float* h2f = (float*)smem;                 // [8][64]
  float* f1o = (float*)(smem + 4096);        // [8][32]
  float* f2o = (float*)(smem + 4096 + 1024); // [8][16]
  if (tid < 256) {
    int o = tid & 31, n = tid >> 5;
    float s = fc1_b[o];
#pragma unroll 8
    for (int k = 0; k < 64; ++k) s = fmaf(h2f[n * 64 + k], fc1_w[o * 64 + k], s);
    f1o[n * 32 + o] = s;
  }
  __syncthreads();
  if (tid < 128) {
    int o = tid & 15, n = tid >> 4;
    float s = fc2_b[o];
#pragma unroll 8
    for (int k = 0; k < 32; ++k) s = fmaf(f1o[n * 32 + k], fc2_w[o * 32 + k], s);
    f2o[n * 16 + o] = s;
  }
  __syncthreads();
  if (tid < 8) {
    float s = fc3_b[0];
#pragma unroll
    for (int k = 0; k < 16; ++k) s = fmaf(f2o[tid * 16 + k], fc3_w[k], s);
    out[blockIdx.x * 8 + tid] = s;
  }
}

extern "C" void kernel_launch(void* const* d_in, const int* in_sizes, int n_in,
                              void* d_out, int out_size, void* d_ws, size_t ws_size,
                              hipStream_t stream) {
  const float* x     = (const float*)d_in[0];
  const float* w_ih1 = (const float*)d_in[1];
  const float* w_hh1 = (const float*)d_in[2];
  const float* b_ih1 = (const float*)d_in[3];
  const float* b_hh1 = (const float*)d_in[4];
  const float* w_ih2 = (const float*)d_in[5];
  const float* w_hh2 = (const float*)d_in[6];
  const float* b_ih2 = (const float*)d_in[7];
  const float* b_hh2 = (const float*)d_in[8];
  const float* fc1_w = (const float*)d_in[9];
  const float* fc1_b = (const float*)d_in[10];
  const float* fc2_w = (const float*)d_in[11];
  const float* fc2_b = (const float*)d_in[12];
  const float* fc3_w = (const float*)d_in[13];
  const float* fc3_b = (const float*)d_in[14];

  hipLaunchKernelGGL(lstm_mfma, dim3(256), dim3(1024), 0, stream,
                     x, w_ih1, w_hh1, b_ih1, b_hh1,
                     w_ih2, w_hh2, b_ih2, b_hh2,
                     fc1_w, fc1_b, fc2_w, fc2_b, fc3_w, fc3_b,
                     (float*)d_out);
}